// Round 1
// baseline (535.025 us; speedup 1.0000x reference)
//
#include <hip/hip_runtime.h>
#include <hip/hip_bf16.h>
#include <cstdint>
#include <cstddef>

typedef __bf16 bf16x8 __attribute__((ext_vector_type(8)));
typedef float  f32x4  __attribute__((ext_vector_type(4)));

static __device__ __forceinline__ float bf2f(unsigned short u){
  unsigned v = ((unsigned)u) << 16;
  return __builtin_bit_cast(float, v);
}
static __device__ __forceinline__ unsigned short f2bf_bits(float f){
  __bf16 h = (__bf16)f;
  return __builtin_bit_cast(unsigned short, h);
}

// ---------------- K0a: build St[s][n] = (sum_e w(s->n)) / max(cnt[n],1) -------
__global__ __launch_bounds__(1024) void k_build_S(const int* __restrict__ ei,
                                                  const float* __restrict__ ea,
                                                  int E, float* __restrict__ St){
  __shared__ float Ssh[40000];
  __shared__ float csh[200];
  __shared__ int is64s;
  const int t = threadIdx.x;
  for (int i = t; i < 40000; i += 1024) Ssh[i] = 0.f;
  if (t < 200) csh[t] = 0.f;
  if (t == 0){
    // detect int64 vs int32 storage of edge_index: int64 -> every odd int32 is 0
    int nz = 0;
    #pragma unroll 1
    for (int i = 1; i < 128; i += 2) nz |= ei[i];
    is64s = (nz == 0) ? 1 : 0;
  }
  __syncthreads();
  const int is64 = is64s;
  for (int e = t; e < E; e += 1024){
    int s, d;
    if (is64){ s = ei[2*e]; d = ei[2*(E+e)]; }
    else     { s = ei[e];   d = ei[E+e];     }
    if ((unsigned)s < 200u && (unsigned)d < 200u){
      atomicAdd(&Ssh[s*200 + d], ea[e]);
      atomicAdd(&csh[d], 1.f);
    }
  }
  __syncthreads();
  for (int i = t; i < 40000; i += 1024){
    int n = i % 200;
    St[i] = Ssh[i] / fmaxf(csh[n], 1.f);
  }
}

// ---------------- K0b: x (f32) -> Xb (bf16, 256 rows, XOR-swizzled layout) ----
// layout: byte(r,k) = r*32768 + (k/64)*128 + ((slot ^ (r&7))*16 + (k%8)*2, slot=(k%64)/8
__global__ __launch_bounds__(256) void k_xb(const float* __restrict__ x,
                                            unsigned char* __restrict__ Xb){
  int idx0 = blockIdx.x*256 + threadIdx.x;
  for (int idx = idx0; idx < 256*2048; idx += 256*256){
    int r  = idx >> 11;
    int sl = idx & 2047;
    int kc = sl >> 3, s = sl & 7;
    float4 v0 = {0.f,0.f,0.f,0.f}, v1 = {0.f,0.f,0.f,0.f};
    if (r < 200){
      const float* p = x + (size_t)r*16384 + kc*64 + s*8;
      v0 = *(const float4*)p;
      v1 = *(const float4*)(p + 4);
    }
    union { uint4 u; __bf16 h[8]; } pk;
    pk.h[0]=(__bf16)v0.x; pk.h[1]=(__bf16)v0.y; pk.h[2]=(__bf16)v0.z; pk.h[3]=(__bf16)v0.w;
    pk.h[4]=(__bf16)v1.x; pk.h[5]=(__bf16)v1.y; pk.h[6]=(__bf16)v1.z; pk.h[7]=(__bf16)v1.w;
    *(uint4*)(Xb + (size_t)r*32768 + kc*128 + ((s ^ (r & 7)) << 4)) = pk.u;
  }
}

// ---------------- GEMM: Cpart[ks][224][NOUT] (bf16) = A(224 x K) * [Wl;Wr]^T ---
// A: pre-swizzled bf16 source (256 rows x KDIM), rowbytes = KDIM*2
template<int BN, int KSPLIT, int KDIM, int NOUT, int NITER>
__global__ __launch_bounds__(512, 2) void k_gemm(const unsigned char* __restrict__ Asrc,
                                                 const float* __restrict__ Wl,
                                                 const float* __restrict__ Wr,
                                                 unsigned short* __restrict__ Cpart){
  constexpr int ROWB   = KDIM * 2;
  constexpr int BBYTES = BN * 128;
  constexpr int STAGE  = 32768 + BBYTES;
  constexpr int NL     = BN / 32;     // B float4 loads per thread per stage
  constexpr int NSTR   = BN / 64;     // 16-col strips per wave (4 N-groups)
  constexpr int NT2    = (NOUT/2) / BN;
  __shared__ unsigned char smem[2*STAGE];

  const int tid = threadIdx.x;
  const int bid = blockIdx.x;
  const int ks    = bid & (KSPLIT - 1);   // XCD-aligned k-split (same ks per XCD)
  const int ntile = bid / KSPLIT;
  const float* W = (ntile < NT2) ? (Wl + (size_t)ntile*BN*KDIM)
                                 : (Wr + (size_t)(ntile - NT2)*BN*KDIM);
  const int kc0 = ks * NITER;

  float4 aS[4];
  float4 bS[NL];

  auto issueA = [&](int kc){
    #pragma unroll
    for (int i = 0; i < 4; i++){
      int r = i*64 + (tid >> 3);
      aS[i] = *(const float4*)(Asrc + (size_t)r*ROWB + (size_t)kc*128 + (tid & 7)*16);
    }
  };
  auto issueB = [&](int kc){
    #pragma unroll
    for (int L = 0; L < NL; L++){
      int c = L*8192 + tid*16;
      int o = c >> 8;
      int kb = c & 255;
      bS[L] = *(const float4*)(W + (size_t)o*KDIM + kc*64 + (kb >> 2));
    }
  };
  auto writeA = [&](unsigned char* Ab){
    #pragma unroll
    for (int i = 0; i < 4; i++)
      *(float4*)(Ab + i*8192 + tid*16) = aS[i];
  };
  auto writeB = [&](unsigned char* Bb){
    #pragma unroll
    for (int L = 0; L < NL; L++){
      int c = L*8192 + tid*16;
      int o = c >> 8;
      int kb = c & 255;
      int slot = kb >> 5;
      int rem8 = (kb >> 1) & 15;   // 0 or 8
      union { uint2 u; __bf16 h[4]; } p;
      p.h[0] = (__bf16)bS[L].x; p.h[1] = (__bf16)bS[L].y;
      p.h[2] = (__bf16)bS[L].z; p.h[3] = (__bf16)bS[L].w;
      *(uint2*)(Bb + o*128 + (((slot ^ (o & 7)) << 4) | rem8)) = p.u;
    }
  };

  const int lane = tid & 63;
  const int wid  = tid >> 6;
  const int mg   = wid >> 2;            // 0..1  (M half)
  const int ng   = wid & 3;             // 0..3  (N group)
  const int l15  = lane & 15;
  const int sx0  = (((lane >> 4) ^ (lane & 7)) << 4);
  const int sx1  = ((((lane >> 4) + 4) ^ (lane & 7)) << 4);
  const int mbase = mg * 112;
  const int nbase = ng * (BN/4);

  f32x4 acc[7][NSTR];
  #pragma unroll
  for (int mt = 0; mt < 7; mt++)
    #pragma unroll
    for (int ns = 0; ns < NSTR; ns++)
      acc[mt][ns] = (f32x4){0.f,0.f,0.f,0.f};

  auto compute = [&](const unsigned char* Ab, const unsigned char* Bb){
    #pragma unroll
    for (int kst = 0; kst < 2; kst++){
      const int sx = kst ? sx1 : sx0;
      bf16x8 bf[NSTR];
      #pragma unroll
      for (int ns = 0; ns < NSTR; ns++)
        bf[ns] = *(const bf16x8*)(Bb + (nbase + ns*16 + l15)*128 + sx);
      #pragma unroll
      for (int mt = 0; mt < 7; mt++){
        bf16x8 af = *(const bf16x8*)(Ab + (mbase + mt*16 + l15)*128 + sx);
        #pragma unroll
        for (int ns = 0; ns < NSTR; ns++)
          acc[mt][ns] = __builtin_amdgcn_mfma_f32_16x16x32_bf16(af, bf[ns], acc[mt][ns], 0, 0, 0);
      }
    }
  };

  // prologue: stage 0 into buf0, issue stage 1
  issueA(kc0); issueB(kc0);
  writeA(smem); writeB(smem + 32768);
  if (NITER > 1){ issueA(kc0 + 1); issueB(kc0 + 1); }
  __syncthreads();

  int cur = 0;
  for (int i = 0; i < NITER; i++){
    unsigned char* Ab = smem + cur*STAGE;
    compute(Ab, Ab + 32768);
    __syncthreads();                       // everyone done reading buf[cur]; drains vm (needed below anyway)
    if (i + 1 < NITER){
      unsigned char* nb_ = smem + (cur ^ 1)*STAGE;
      writeA(nb_); writeB(nb_ + 32768);
    }
    __syncthreads();                       // buf[cur^1] staged for next iter; nothing in vm -> cheap
    if (i + 2 < NITER){ issueA(kc0 + i + 2); issueB(kc0 + i + 2); }  // stays in flight across next compute
    cur ^= 1;
  }

  // epilogue: bf16 partial store
  const int rbase = ks * 224;
  #pragma unroll
  for (int mt = 0; mt < 7; mt++)
    #pragma unroll
    for (int ns = 0; ns < NSTR; ns++)
      #pragma unroll
      for (int j = 0; j < 4; j++){
        int row = mbase + mt*16 + (lane >> 4)*4 + j;
        int col = ntile*BN + nbase + ns*16 + l15;
        Cpart[(size_t)(rbase + row)*NOUT + col] = f2bf_bits(acc[mt][ns][j]);
      }
}

// ---------------- reduce K partials (bf16) -> f32 ------------------------------
template<int KS>
__global__ __launch_bounds__(256) void k_reduce(const unsigned short* __restrict__ cp,
                                                float* __restrict__ out, int n8){
  const size_t part = (size_t)n8 * 8;
  int stride = gridDim.x * blockDim.x;
  for (int idx = blockIdx.x*blockDim.x + threadIdx.x; idx < n8; idx += stride){
    float a[8] = {0.f,0.f,0.f,0.f,0.f,0.f,0.f,0.f};
    #pragma unroll
    for (int ksi = 0; ksi < KS; ksi++){
      union { uint4 v; unsigned short s[8]; } u;
      u.v = *(const uint4*)(cp + ksi*part + (size_t)idx*8);
      #pragma unroll
      for (int j = 0; j < 8; j++) a[j] += bf2f(u.s[j]);
    }
    float4 lo = {a[0],a[1],a[2],a[3]};
    float4 hi = {a[4],a[5],a[6],a[7]};
    *(float4*)(out + (size_t)idx*8)     = lo;
    *(float4*)(out + (size_t)idx*8 + 4) = hi;
  }
}

// ---------------- h1 = relu(S@P + Q + b1) -> H1b (swizzled bf16) ---------------
__global__ __launch_bounds__(256) void k_h1(const float* __restrict__ PQ,
                                            const float* __restrict__ St,
                                            const float* __restrict__ b1,
                                            unsigned char* __restrict__ H1b){
  const int och = blockIdx.x >> 2, nsp = blockIdx.x & 3;
  const int w = threadIdx.x >> 6, lane = threadIdx.x & 63;
  const int o = och*64 + lane;
  const int nb = __builtin_amdgcn_readfirstlane(nsp*50 + w*13);
  const int ncnt = (w == 3) ? 11 : 13;
  float acc[13];
  #pragma unroll
  for (int i = 0; i < 13; i++) acc[i] = 0.f;
  for (int s = 0; s < 200; s++){
    float p = PQ[(size_t)s*8192 + o];
    #pragma unroll
    for (int i = 0; i < 13; i++)
      if (i < ncnt) acc[i] = fmaf(St[s*200 + nb + i], p, acc[i]);
  }
  float bo = b1[o];
  #pragma unroll
  for (int i = 0; i < 13; i++)
    if (i < ncnt){
      int r = nb + i;
      float h = acc[i] + PQ[(size_t)r*8192 + 4096 + o] + bo;
      h = fmaxf(h, 0.f);
      int kc = o >> 6, wi = o & 63, slot = wi >> 3, rem = wi & 7;
      *(__bf16*)(H1b + (size_t)r*8192 + kc*128 + (((slot ^ (r & 7)) << 4) | (rem*2))) = (__bf16)h;
    }
}

// ---------------- h2 = S@R + T + b2 (no relu) ----------------------------------
__global__ __launch_bounds__(256) void k_h2(const float* __restrict__ RT,
                                            const float* __restrict__ St,
                                            const float* __restrict__ b2,
                                            float* __restrict__ h2){
  const int cch = blockIdx.x >> 2, nsp = blockIdx.x & 3;
  const int w = threadIdx.x >> 6, lane = threadIdx.x & 63;
  const int c = cch*64 + lane;
  const int nb = __builtin_amdgcn_readfirstlane(nsp*50 + w*13);
  const int ncnt = (w == 3) ? 11 : 13;
  float acc[13];
  #pragma unroll
  for (int i = 0; i < 13; i++) acc[i] = 0.f;
  for (int s = 0; s < 200; s++){
    float r = RT[(size_t)s*1024 + c];
    #pragma unroll
    for (int i = 0; i < 13; i++)
      if (i < ncnt) acc[i] = fmaf(St[s*200 + nb + i], r, acc[i]);
  }
  float bc = b2[c];
  #pragma unroll
  for (int i = 0; i < 13; i++)
    if (i < ncnt){
      int n = nb + i;
      h2[(size_t)n*512 + c] = acc[i] + RT[(size_t)n*1024 + 512 + c] + bc;
    }
}

// ---------------- classifier: out[512,10] = mlp(h2^T) --------------------------
__global__ __launch_bounds__(512) void k_cls(const float* __restrict__ h2,
    const float* __restrict__ Wc1, const float* __restrict__ bc1,
    const float* __restrict__ Wc2, const float* __restrict__ bc2,
    const float* __restrict__ Wc3, const float* __restrict__ bc3,
    float* __restrict__ out){
  __shared__ float zt[64*201];
  __shared__ float z1[64*101];
  __shared__ float z2[64*51];
  const int cb = blockIdx.x * 64;
  const int t = threadIdx.x;
  for (int idx = t; idx < 64*200; idx += 512){
    int n = idx >> 6, cl = idx & 63;
    zt[cl*201 + n] = h2[(size_t)n*512 + cb + cl];
  }
  __syncthreads();
  const int w = t >> 6, c = t & 63;
  {
    const int jb = __builtin_amdgcn_readfirstlane(w*13);
    const int jn = (w == 7) ? 9 : 13;   // 7*13+9 = 100
    float a[13];
    #pragma unroll
    for (int j = 0; j < 13; j++) a[j] = (j < jn) ? bc1[jb + j] : 0.f;
    for (int n = 0; n < 200; n++){
      float v = zt[c*201 + n];
      #pragma unroll
      for (int j = 0; j < 13; j++)
        if (j < jn) a[j] = fmaf(v, Wc1[(jb + j)*200 + n], a[j]);
    }
    #pragma unroll
    for (int j = 0; j < 13; j++)
      if (j < jn) z1[c*101 + jb + j] = fmaxf(a[j], 0.f);
  }
  __syncthreads();
  {
    const int jb = __builtin_amdgcn_readfirstlane(w*7);
    const int jn = (w == 7) ? 1 : 7;    // 7*7+1 = 50
    float a[7];
    #pragma unroll
    for (int j = 0; j < 7; j++) a[j] = (j < jn) ? bc2[jb + j] : 0.f;
    for (int n = 0; n < 100; n++){
      float v = z1[c*101 + n];
      #pragma unroll
      for (int j = 0; j < 7; j++)
        if (j < jn) a[j] = fmaf(v, Wc2[(jb + j)*100 + n], a[j]);
    }
    #pragma unroll
    for (int j = 0; j < 7; j++)
      if (j < jn) z2[c*51 + jb + j] = fmaxf(a[j], 0.f);
  }
  __syncthreads();
  if (w < 5){
    const int jb = __builtin_amdgcn_readfirstlane(w*2);
    float a[2] = { bc3[jb], bc3[jb + 1] };
    for (int n = 0; n < 50; n++){
      float v = z2[c*51 + n];
      a[0] = fmaf(v, Wc3[jb*50 + n], a[0]);
      a[1] = fmaf(v, (jb + 1)*50 + n >= 0 ? Wc3[(jb + 1)*50 + n] : 0.f, a[1]);
    }
    out[(size_t)(cb + c)*10 + jb]     = a[0];
    out[(size_t)(cb + c)*10 + jb + 1] = a[1];
  }
}

// ---------------- host launch ---------------------------------------------------
extern "C" void kernel_launch(void* const* d_in, const int* in_sizes, int n_in,
                              void* d_out, int out_size, void* d_ws, size_t ws_size,
                              hipStream_t stream){
  (void)n_in; (void)out_size; (void)ws_size;
  const float* x   = (const float*)d_in[0];
  const int*   ei  = (const int*)  d_in[1];
  const float* ea  = (const float*)d_in[2];
  const float* W1l = (const float*)d_in[3];
  const float* W1r = (const float*)d_in[4];
  const float* b1  = (const float*)d_in[5];
  const float* W2l = (const float*)d_in[6];
  const float* W2r = (const float*)d_in[7];
  const float* b2  = (const float*)d_in[8];
  const float* Wc1 = (const float*)d_in[9];
  const float* bc1 = (const float*)d_in[10];
  const float* Wc2 = (const float*)d_in[11];
  const float* bc2 = (const float*)d_in[12];
  const float* Wc3 = (const float*)d_in[13];
  const float* bc3 = (const float*)d_in[14];
  float* out = (float*)d_out;
  char* ws = (char*)d_ws;
  const int E = in_sizes[1] / 2;

  constexpr size_t ST_OFF  = 0;                                   // 160000 B
  constexpr size_t XB_OFF  = 262144;                              // 8 MiB (256 x 16384 bf16)
  constexpr size_t CP1_OFF = XB_OFF + (size_t)256*16384*2;        // 8 x 224 x 8192 bf16
  constexpr size_t PQ_OFF  = CP1_OFF + (size_t)8*224*8192*2;      // 224 x 8192 f32
  constexpr size_t H1B_OFF = PQ_OFF + (size_t)224*8192*4;         // 256 x 4096 bf16
  constexpr size_t CP2_OFF = H1B_OFF + (size_t)256*4096*2;        // 16 x 224 x 1024 bf16
  constexpr size_t RT_OFF  = CP2_OFF + (size_t)16*224*1024*2;     // 224 x 1024 f32
  constexpr size_t H2_OFF  = RT_OFF + (size_t)224*1024*4;         // 200 x 512 f32

  float*          St  = (float*)(ws + ST_OFF);
  unsigned char*  Xb  = (unsigned char*)(ws + XB_OFF);
  unsigned short* Cp1 = (unsigned short*)(ws + CP1_OFF);
  float*          PQ  = (float*)(ws + PQ_OFF);
  unsigned char*  H1b = (unsigned char*)(ws + H1B_OFF);
  unsigned short* Cp2 = (unsigned short*)(ws + CP2_OFF);
  float*          RT  = (float*)(ws + RT_OFF);
  float*          h2  = (float*)(ws + H2_OFF);

  k_build_S<<<dim3(1),   dim3(1024), 0, stream>>>(ei, ea, E, St);
  k_xb     <<<dim3(256), dim3(256),  0, stream>>>(x, Xb);
  k_gemm<256, 8, 16384, 8192, 32><<<dim3(256), dim3(512), 0, stream>>>(Xb, W1l, W1r, Cp1);
  k_reduce<8> <<<dim3(256), dim3(256), 0, stream>>>(Cp1, PQ, 224*8192/8);
  k_h1     <<<dim3(256), dim3(256),  0, stream>>>(PQ, St, b1, H1b);
  k_gemm<64, 16, 4096, 1024, 4><<<dim3(256), dim3(512), 0, stream>>>(H1b, W2l, W2r, Cp2);
  k_reduce<16><<<dim3(64), dim3(256), 0, stream>>>(Cp2, RT, 224*1024/8);
  k_h2     <<<dim3(32),  dim3(256),  0, stream>>>(RT, St, b2, h2);
  k_cls    <<<dim3(8),   dim3(512),  0, stream>>>(h2, Wc1, bc1, Wc2, bc2, Wc3, bc3, out);
}